// Round 3
// baseline (333.598 us; speedup 1.0000x reference)
//
#include <hip/hip_runtime.h>
#include <stdint.h>

typedef _Float16 f16;
typedef f16 f16x8 __attribute__((ext_vector_type(8)));
typedef float f32x4 __attribute__((ext_vector_type(4)));

#define MFMA(a,b,c) __builtin_amdgcn_mfma_f32_16x16x32_f16(a, b, c, 0, 0, 0)

__device__ __forceinline__ float sigmoidf_(float z) { return 1.0f / (1.0f + __expf(-z)); }

// ---------------------------------------------------------------------------
// prep: scale[b]; weights -> f16; zero out[0..63] and flags.
// Wopt: fragment-permuted [Aq;Ak;Av] (192x2048):
//   element (r,k) at ((rt*64+kc)*16+(r&15))*32 + ((k>>3)&3)*8 + (k&7),
//   rt=r>>4, kc=k>>5. A B-frag load is then 1KB contiguous per wave.
// Wsm = 9 x (64x64): Aq1,Ak1,Av1,Aq5,Ak5,Av5,Ao,Ao1,Ao5
// ---------------------------------------------------------------------------
__global__ void prep_kernel(const float* __restrict__ L,
    const float* __restrict__ Aq, const float* __restrict__ Ak, const float* __restrict__ Av,
    const float* __restrict__ Aq1, const float* __restrict__ Ak1, const float* __restrict__ Av1,
    const float* __restrict__ Aq5, const float* __restrict__ Ak5, const float* __restrict__ Av5,
    const float* __restrict__ Ao, const float* __restrict__ Ao1, const float* __restrict__ Ao5,
    float* __restrict__ scale, f16* __restrict__ Wopt, f16* __restrict__ Wsm,
    float* __restrict__ out, unsigned int* __restrict__ flagg)
{
  __shared__ float r4[4];
  int blk = blockIdx.x, t = threadIdx.x;
  if (blk < 64) {
    float v = (L[blk * 512 + t] >= 1.0f) ? 1.0f : 0.0f;
    #pragma unroll
    for (int off = 32; off; off >>= 1) v += __shfl_down(v, off);
    if ((t & 63) == 0) r4[t >> 6] = v;
    __syncthreads();
    if (t == 0) scale[blk] = sqrtf(r4[0] + r4[1] + r4[2] + r4[3] + 1.0f);
  } else if (blk < 160) {
    int base = (blk - 64) * 4096;
    for (int i = 0; i < 16; i++) {
      int idx = base + t + i * 256;
      int r = idx >> 11, k = idx & 2047;
      float v = (r < 64) ? Aq[r * 2048 + k]
              : (r < 128) ? Ak[(r - 64) * 2048 + k]
              : Av[(r - 128) * 2048 + k];
      int rt = r >> 4, lr = r & 15, kc = k >> 5, qq = (k >> 3) & 3, jj = k & 7;
      Wopt[((rt * 64 + kc) * 16 + lr) * 32 + qq * 8 + jj] = (f16)v;
    }
  } else if (blk < 169) {
    int j = blk - 160;
    const float* s = (j == 0) ? Aq1 : (j == 1) ? Ak1 : (j == 2) ? Av1 : (j == 3) ? Aq5
                   : (j == 4) ? Ak5 : (j == 5) ? Av5 : (j == 6) ? Ao : (j == 7) ? Ao1 : Ao5;
    for (int i = 0; i < 16; i++) { int idx = t + i * 256; Wsm[j * 4096 + idx] = (f16)s[idx]; }
  } else {
    if (t < 64) out[t] = 0.0f;
    else if (t < 128) flagg[t - 64] = 0u;
  }
}

// ---------------------------------------------------------------------------
// qkv1 v2: barrier-free, LDS-free streaming MFMA GEMM.
// Block (g,b): n-slice of 32 (2 n-tiles), all 192 r; wave w owns r-tiles
// w*3..w*3+2. A-frags (x, fp32) loaded direct from global + in-register f16
// convert (4x wave redundancy -> L1/L2). B-frags from Wopt: contiguous 1KB.
// ---------------------------------------------------------------------------
__global__ __launch_bounds__(256) void qkv1_kernel(const float* __restrict__ x,
    const f16* __restrict__ Wopt, f16* __restrict__ Qt, f16* __restrict__ Kt,
    f16* __restrict__ Vg)
{
  int b = blockIdx.y, n0 = blockIdx.x * 32;
  int t = threadIdx.x, lane = t & 63, w = t >> 6;
  int l15 = lane & 15, q = lane >> 4;
  f32x4 acc[2][3] = {};
  const float* xb0 = x + (size_t)b * 524288 + n0 + l15;
  const float* xb1 = xb0 + 16;
  const f16* wb = Wopt + ((size_t)(w * 3) * 1024 + l15) * 32 + q * 8;

  #pragma unroll 2
  for (int kc = 0; kc < 64; kc++) {
    int f = kc * 32 + q * 8;
    const float* p0 = xb0 + (size_t)f * 256;
    const float* p1 = xb1 + (size_t)f * 256;
    f16x8 af0, af1;
    #pragma unroll
    for (int j = 0; j < 8; j++) af0[j] = (f16)p0[j * 256];
    #pragma unroll
    for (int j = 0; j < 8; j++) af1[j] = (f16)p1[j * 256];
    f16x8 bf[3];
    #pragma unroll
    for (int j = 0; j < 3; j++)
      bf[j] = *(const f16x8*)(wb + (size_t)j * 32768 + kc * 512);
    #pragma unroll
    for (int j = 0; j < 3; j++) {
      acc[0][j] = MFMA(af0, bf[j], acc[0][j]);
      acc[1][j] = MFMA(af1, bf[j], acc[1][j]);
    }
  }

  #pragma unroll
  for (int nt = 0; nt < 2; nt++)
    #pragma unroll
    for (int j = 0; j < 3; j++) {
      int rr = (w * 3 + j) * 16 + l15;
      float s[4];
      #pragma unroll
      for (int reg = 0; reg < 4; reg++) s[reg] = sigmoidf_(acc[nt][j][reg]);
      int nbase = n0 + nt * 16 + q * 4;
      if (rr < 64) {
        #pragma unroll
        for (int reg = 0; reg < 4; reg++)
          Qt[(size_t)b * 16384 + (size_t)(nbase + reg) * 64 + rr] = (f16)s[reg];
      } else if (rr < 128) {
        #pragma unroll
        for (int reg = 0; reg < 4; reg++)
          Kt[(size_t)b * 16384 + (size_t)(nbase + reg) * 64 + (rr - 64)] = (f16)s[reg];
      } else {
        union { f16 h[4]; uint2 u; } pk;
        #pragma unroll
        for (int reg = 0; reg < 4; reg++) pk.h[reg] = (f16)s[reg];
        *(uint2*)(Vg + (size_t)b * 16384 + (size_t)(rr - 128) * 256 + nbase) = pk.u;
      }
    }
}

// ---------------------------------------------------------------------------
// attn_fused: all 3 layers in one kernel. grid (4,64), 512 threads, ~126 KB
// LDS -> exactly 1 block/CU, 256 blocks co-resident (safe spin barrier).
// Layer boundary: store M-slice -> threadfence -> atomicAdd(flag[b]) ->
// acquire-spin to 4*(l+1) -> restage. MA holds layer-0 M, MB layer-1 M.
// ---------------------------------------------------------------------------
__global__ __launch_bounds__(512) void attn_fused(const float* __restrict__ x,
    const float* __restrict__ scale, const f16* __restrict__ Wsm,
    const f16* __restrict__ Qtg, const f16* __restrict__ Ktg, const f16* __restrict__ Vgg,
    f16* __restrict__ MA, f16* __restrict__ MB,
    unsigned int* __restrict__ flagg, float* __restrict__ out)
{
  int g = blockIdx.x, b = blockIdx.y, n0 = g * 64;
  int t = threadIdx.x, lane = t & 63, w = t >> 6;
  int l15 = lane & 15, q = lane >> 4;
  __shared__ f16 KT[256 * 72];
  __shared__ f16 SM[256 * 72];
  __shared__ f16 VM[64 * 264];
  __shared__ f16 QT[64 * 72];
  __shared__ f16 OT[64 * 72];
  __shared__ float denomS[64];

  float sinv = 1.0f / scale[b];

  #pragma unroll 1
  for (int l = 0; l < 3; l++) {
    if (t < 64) denomS[t] = 0.0f;

    const f16* Wq = Wsm + (size_t)(l == 1 ? 0 : 3) * 4096;
    const f16* Wk = Wsm + (size_t)(l == 1 ? 1 : 4) * 4096;
    const f16* Wv = Wsm + (size_t)(l == 1 ? 2 : 5) * 4096;
    const f16* Wo = Wsm + (size_t)(l == 0 ? 6 : (l == 1 ? 7 : 8)) * 4096;

    if (l == 0) {
      const uint4* qs = (const uint4*)(Qtg + (size_t)b * 16384 + (size_t)n0 * 64);
      { int n = t >> 3, c = t & 7; *(uint4*)&QT[n * 72 + c * 8] = qs[t]; }
      const uint4* ks = (const uint4*)(Ktg + (size_t)b * 16384);
      const uint4* vs = (const uint4*)(Vgg + (size_t)b * 16384);
      #pragma unroll
      for (int i = 0; i < 4; i++) {
        int id = t + i * 512;
        int m = id >> 3, c = id & 7;
        *(uint4*)&KT[m * 72 + c * 8] = ks[id];
        int r = id >> 5, c2 = id & 31;
        *(uint4*)&VM[r * 264 + c2 * 8] = vs[id];
      }
      __syncthreads();
    } else {
      const f16* Min = (l == 1) ? MA : MB;
      const uint4* ms = (const uint4*)(Min + (size_t)b * 16384);
      #pragma unroll
      for (int i = 0; i < 4; i++) {
        int id = t + i * 512, m = id >> 3, c = id & 7;
        *(uint4*)&SM[m * 72 + c * 8] = ms[id];
      }
      __syncthreads();
      if (w < 4) {
        // KT[m][r] = sigmoid( sum_s M^T[m][s] * Wk[r][s] )
        f16x8 bk[4][2];
        #pragma unroll
        for (int rt = 0; rt < 4; rt++) {
          bk[rt][0] = *(const f16x8*)(Wk + (rt * 16 + l15) * 64 + q * 8);
          bk[rt][1] = *(const f16x8*)(Wk + (rt * 16 + l15) * 64 + 32 + q * 8);
        }
        #pragma unroll
        for (int mi = 0; mi < 4; mi++) {
          int mt = w * 4 + mi;
          f16x8 a0 = *(const f16x8*)&SM[(mt * 16 + l15) * 72 + q * 8];
          f16x8 a1 = *(const f16x8*)&SM[(mt * 16 + l15) * 72 + 32 + q * 8];
          #pragma unroll
          for (int rt = 0; rt < 4; rt++) {
            f32x4 acc = {}; acc = MFMA(a0, bk[rt][0], acc); acc = MFMA(a1, bk[rt][1], acc);
            #pragma unroll
            for (int reg = 0; reg < 4; reg++)
              KT[(mt * 16 + q * 4 + reg) * 72 + rt * 16 + l15] = (f16)sigmoidf_(acc[reg]);
          }
        }
      } else {
        // VM[r][m] = sigmoid( sum_s Wv[r][s] * M^T[m][s] )
        f16x8 av[4][2];
        #pragma unroll
        for (int rt = 0; rt < 4; rt++) {
          av[rt][0] = *(const f16x8*)(Wv + (rt * 16 + l15) * 64 + q * 8);
          av[rt][1] = *(const f16x8*)(Wv + (rt * 16 + l15) * 64 + 32 + q * 8);
        }
        #pragma unroll
        for (int mi = 0; mi < 4; mi++) {
          int mt = (w - 4) * 4 + mi;
          f16x8 b0 = *(const f16x8*)&SM[(mt * 16 + l15) * 72 + q * 8];
          f16x8 b1 = *(const f16x8*)&SM[(mt * 16 + l15) * 72 + 32 + q * 8];
          #pragma unroll
          for (int rt = 0; rt < 4; rt++) {
            f32x4 acc = {}; acc = MFMA(av[rt][0], b0, acc); acc = MFMA(av[rt][1], b1, acc);
            #pragma unroll
            for (int reg = 0; reg < 4; reg++)
              VM[(rt * 16 + q * 4 + reg) * 264 + mt * 16 + l15] = (f16)sigmoidf_(acc[reg]);
          }
        }
      }
      // QT for local rows
      {
        int nt = w >> 1;
        f16x8 a0 = *(const f16x8*)&SM[(n0 + nt * 16 + l15) * 72 + q * 8];
        f16x8 a1 = *(const f16x8*)&SM[(n0 + nt * 16 + l15) * 72 + 32 + q * 8];
        #pragma unroll
        for (int j = 0; j < 2; j++) {
          int rt = (w & 1) * 2 + j;
          f16x8 b0 = *(const f16x8*)(Wq + (rt * 16 + l15) * 64 + q * 8);
          f16x8 b1 = *(const f16x8*)(Wq + (rt * 16 + l15) * 64 + 32 + q * 8);
          f32x4 acc = {}; acc = MFMA(a0, b0, acc); acc = MFMA(a1, b1, acc);
          #pragma unroll
          for (int reg = 0; reg < 4; reg++)
            QT[(nt * 16 + q * 4 + reg) * 72 + rt * 16 + l15] = (f16)sigmoidf_(acc[reg]);
        }
      }
      __syncthreads();
    }

    // S = exp(QK^T * sinv) -> SM as [64][264]; denom via shfl + LDS atomic
    {
      int nt = w >> 1;
      f16x8 a0 = *(const f16x8*)&QT[(nt * 16 + l15) * 72 + q * 8];
      f16x8 a1 = *(const f16x8*)&QT[(nt * 16 + l15) * 72 + 32 + q * 8];
      float dsum[4] = {0.f, 0.f, 0.f, 0.f};
      #pragma unroll
      for (int mi = 0; mi < 8; mi++) {
        int mt = (w & 1) * 8 + mi;
        f16x8 b0 = *(const f16x8*)&KT[(mt * 16 + l15) * 72 + q * 8];
        f16x8 b1 = *(const f16x8*)&KT[(mt * 16 + l15) * 72 + 32 + q * 8];
        f32x4 acc = {}; acc = MFMA(a0, b0, acc); acc = MFMA(a1, b1, acc);
        #pragma unroll
        for (int reg = 0; reg < 4; reg++) {
          float e = __expf(acc[reg] * sinv);
          dsum[reg] += e;
          SM[(nt * 16 + q * 4 + reg) * 264 + mt * 16 + l15] = (f16)e;
        }
      }
      #pragma unroll
      for (int reg = 0; reg < 4; reg++) {
        #pragma unroll
        for (int mask = 1; mask < 16; mask <<= 1) dsum[reg] += __shfl_xor(dsum[reg], mask);
      }
      if (l15 == 0) {
        #pragma unroll
        for (int reg = 0; reg < 4; reg++) atomicAdd(&denomS[nt * 16 + q * 4 + reg], dsum[reg]);
      }
    }
    __syncthreads();

    // AV: o^T[n][r] = sum_m S[n][m] VM[r][m]; normalize -> OT
    {
      int nt = w >> 1;
      f32x4 oacc[2] = {};
      #pragma unroll
      for (int kc = 0; kc < 8; kc++) {
        f16x8 af = *(const f16x8*)&SM[(nt * 16 + l15) * 264 + kc * 32 + q * 8];
        #pragma unroll
        for (int j = 0; j < 2; j++) {
          int rt = (w & 1) * 2 + j;
          f16x8 bf = *(const f16x8*)&VM[(rt * 16 + l15) * 264 + kc * 32 + q * 8];
          oacc[j] = MFMA(af, bf, oacc[j]);
        }
      }
      #pragma unroll
      for (int j = 0; j < 2; j++) {
        int rt = (w & 1) * 2 + j;
        #pragma unroll
        for (int reg = 0; reg < 4; reg++) {
          int row = nt * 16 + q * 4 + reg;
          OT[row * 72 + rt * 16 + l15] = (f16)(oacc[j][reg] / denomS[row]);
        }
      }
    }
    __syncthreads();

    // M'[n][s] = silu( sum_r OT[n][r] Wo[s][r] ) -> Mst (QT reused, stride 64)
    f16* Mst = QT;
    {
      int nt = w >> 1;
      f16x8 a0 = *(const f16x8*)&OT[(nt * 16 + l15) * 72 + q * 8];
      f16x8 a1 = *(const f16x8*)&OT[(nt * 16 + l15) * 72 + 32 + q * 8];
      #pragma unroll
      for (int j = 0; j < 2; j++) {
        int st = (w & 1) * 2 + j;
        f16x8 b0 = *(const f16x8*)(Wo + (st * 16 + l15) * 64 + q * 8);
        f16x8 b1 = *(const f16x8*)(Wo + (st * 16 + l15) * 64 + 32 + q * 8);
        f32x4 acc = {}; acc = MFMA(a0, b0, acc); acc = MFMA(a1, b1, acc);
        #pragma unroll
        for (int reg = 0; reg < 4; reg++) {
          float z = acc[reg];
          Mst[(nt * 16 + q * 4 + reg) * 64 + st * 16 + l15] = (f16)(z * sigmoidf_(z));
        }
      }
    }
    __syncthreads();

    if (l < 2) {
      f16* Mout = (l == 0) ? MA : MB;
      int row = t >> 3, c = t & 7;
      *(uint4*)(Mout + (size_t)b * 16384 + (size_t)(n0 + row) * 64 + c * 8)
          = *(const uint4*)&Mst[row * 64 + c * 8];
      // inter-block (per-batch) barrier: 4 blocks of batch b
      if (t == 0) {
        __threadfence();
        atomicAdd(&flagg[b], 1u);
        unsigned int target = 4u * (unsigned)(l + 1);
        while (__hip_atomic_load(&flagg[b], __ATOMIC_ACQUIRE, __HIP_MEMORY_SCOPE_AGENT) < target)
          __builtin_amdgcn_s_sleep(2);
        __threadfence();
      }
      __syncthreads();
    } else {
      float contrib = 0.0f;
      if (t < 64) {
        int ntok = n0 + t;
        const f16* row = &Mst[t * 64];
        float d[4] = {0, 0, 0, 0}, pp = 0.0f;
        #pragma unroll
        for (int gg = 0; gg < 8; gg++) {
          f16x8 v = *(const f16x8*)(row + gg * 8);
          float ss = 0.0f;
          #pragma unroll
          for (int k = 0; k < 8; k++) { float f = (float)v[k]; ss += f * f; }
          if (gg < 4) d[gg] = ss; else pp += ss;
        }
        int np = ntok >> 1, c0 = (ntok & 1) * 2;
        const float* xb = x + (size_t)b * 524288 + (size_t)c0 * 256;
        float q1a = xb[np], q1b = xb[256 + np];
        float q2a = xb[128 + np], q2b = xb[384 + np];
        contrib = d[0] * (q1a * q1a + q1b * q1b)
                + (d[1] + d[2]) * (q1a * q2a + q1b * q2b)
                + d[3] * (q2a * q2a + q2b * q2b) + pp;
      }
      if (w == 0) {
        #pragma unroll
        for (int off = 32; off; off >>= 1) contrib += __shfl_down(contrib, off);
        if (lane == 0) atomicAdd(out + b, contrib);
      }
    }
  }
}

// ---------------------------------------------------------------------------
extern "C" void kernel_launch(void* const* d_in, const int* in_sizes, int n_in,
                              void* d_out, int out_size, void* d_ws, size_t ws_size,
                              hipStream_t stream) {
  const float* x   = (const float*)d_in[0];
  const float* L   = (const float*)d_in[1];
  const float* Aq  = (const float*)d_in[2];
  const float* Ak  = (const float*)d_in[3];
  const float* Av  = (const float*)d_in[4];
  const float* Aq1 = (const float*)d_in[5];
  const float* Ak1 = (const float*)d_in[6];
  const float* Av1 = (const float*)d_in[7];
  const float* Aq5 = (const float*)d_in[8];
  const float* Ak5 = (const float*)d_in[9];
  const float* Av5 = (const float*)d_in[10];
  const float* Ao  = (const float*)d_in[11];
  const float* Ao1 = (const float*)d_in[12];
  const float* Ao5 = (const float*)d_in[13];

  char* ws = (char*)d_ws;
  float* scale = (float*)ws;                     // 256 B
  f16* Wopt  = (f16*)(ws + 256);                 // 786432 B
  f16* Wsm   = (f16*)(ws + 786688);              // 73728 B
  f16* Qtg   = (f16*)(ws + 860416);              // 2 MB
  f16* Ktg   = (f16*)(ws + 2957568);             // 2 MB
  f16* Vgg   = (f16*)(ws + 5054720);             // 2 MB
  f16* MbufA = (f16*)(ws + 7151872);             // 2 MB
  f16* MbufB = (f16*)(ws + 9249024);             // 2 MB
  unsigned int* flagg = (unsigned int*)(ws + 11346176);  // 256 B
  float* out = (float*)d_out;

  prep_kernel<<<170, 256, 0, stream>>>(L, Aq, Ak, Av, Aq1, Ak1, Av1,
                                       Aq5, Ak5, Av5, Ao, Ao1, Ao5,
                                       scale, Wopt, Wsm, out, flagg);
  qkv1_kernel<<<dim3(8, 64), 256, 0, stream>>>(x, Wopt, Qtg, Ktg, Vgg);
  attn_fused<<<dim3(4, 64), 512, 0, stream>>>(x, scale, Wsm, Qtg, Ktg, Vgg,
                                              MbufA, MbufB, flagg, out);
}

// Round 4
// 317.881 us; speedup vs baseline: 1.0494x; 1.0494x over previous
//
#include <hip/hip_runtime.h>
#include <stdint.h>

typedef _Float16 f16;
typedef f16 f16x8 __attribute__((ext_vector_type(8)));
typedef float f32x4 __attribute__((ext_vector_type(4)));

#define MFMA(a,b,c) __builtin_amdgcn_mfma_f32_16x16x32_f16(a, b, c, 0, 0, 0)

__device__ __forceinline__ float sigmoidf_(float z) { return 1.0f / (1.0f + __expf(-z)); }

__device__ __forceinline__ uint32_t packh2(float a, float b) {
  return (uint32_t)__builtin_bit_cast(uint16_t, (f16)a)
       | ((uint32_t)__builtin_bit_cast(uint16_t, (f16)b) << 16);
}

// ---------------------------------------------------------------------------
// prep: scale[b]; weights -> f16; zero out[0..63] and flags.
// Wopt: fragment-permuted [Aq;Ak;Av] (192x2048):
//   element (r,k) -> ((rt*64+kc)*16+(r&15))*32 + ((k>>3)&3)*8 + (k&7),
//   rt=r>>4, kc=k>>5. A B-frag load is then 1KB contiguous per wave.
// Wsm = 9 x (64x64): Aq1,Ak1,Av1,Aq5,Ak5,Av5,Ao,Ao1,Ao5
// ---------------------------------------------------------------------------
__global__ void prep_kernel(const float* __restrict__ L,
    const float* __restrict__ Aq, const float* __restrict__ Ak, const float* __restrict__ Av,
    const float* __restrict__ Aq1, const float* __restrict__ Ak1, const float* __restrict__ Av1,
    const float* __restrict__ Aq5, const float* __restrict__ Ak5, const float* __restrict__ Av5,
    const float* __restrict__ Ao, const float* __restrict__ Ao1, const float* __restrict__ Ao5,
    float* __restrict__ scale, f16* __restrict__ Wopt, f16* __restrict__ Wsm,
    float* __restrict__ out, unsigned int* __restrict__ flagg)
{
  __shared__ float r4[4];
  int blk = blockIdx.x, t = threadIdx.x;
  if (blk < 64) {
    float v = (L[blk * 512 + t] >= 1.0f) ? 1.0f : 0.0f;
    #pragma unroll
    for (int off = 32; off; off >>= 1) v += __shfl_down(v, off);
    if ((t & 63) == 0) r4[t >> 6] = v;
    __syncthreads();
    if (t == 0) scale[blk] = sqrtf(r4[0] + r4[1] + r4[2] + r4[3] + 1.0f);
  } else if (blk < 160) {
    int base = (blk - 64) * 4096;
    for (int i = 0; i < 16; i++) {
      int idx = base + t + i * 256;
      int r = idx >> 11, k = idx & 2047;
      float v = (r < 64) ? Aq[r * 2048 + k]
              : (r < 128) ? Ak[(r - 64) * 2048 + k]
              : Av[(r - 128) * 2048 + k];
      int rt = r >> 4, lr = r & 15, kc = k >> 5, qq = (k >> 3) & 3, jj = k & 7;
      Wopt[((rt * 64 + kc) * 16 + lr) * 32 + qq * 8 + jj] = (f16)v;
    }
  } else if (blk < 169) {
    int j = blk - 160;
    const float* s = (j == 0) ? Aq1 : (j == 1) ? Ak1 : (j == 2) ? Av1 : (j == 3) ? Aq5
                   : (j == 4) ? Ak5 : (j == 5) ? Av5 : (j == 6) ? Ao : (j == 7) ? Ao1 : Ao5;
    for (int i = 0; i < 16; i++) { int idx = t + i * 256; Wsm[j * 4096 + idx] = (f16)s[idx]; }
  } else {
    if (t < 64) out[t] = 0.0f;
    else if (t < 128) flagg[t - 64] = 0u;
  }
}

// ---------------------------------------------------------------------------
// qkv1 v3: LDS-transpose staging, double-buffered, prefetch-distance-2.
// Block (g,b): n-slice of 32; wave w owns r-tiles w*3..w*3+2.
// x rows staged coalesced (dword, 128B segments) -> f16 transpose in LDS;
// B-frags from Wopt (contiguous 1KB/wave, L2-resident). 1 barrier/chunk.
// ---------------------------------------------------------------------------
__global__ __launch_bounds__(256) void qkv1_kernel(const float* __restrict__ x,
    const f16* __restrict__ Wopt, f16* __restrict__ Qt, f16* __restrict__ Kt,
    f16* __restrict__ Vg)
{
  int b = blockIdx.y, n0 = blockIdx.x * 32;
  int t = threadIdx.x, lane = t & 63, w = t >> 6;
  int l15 = lane & 15, q = lane >> 4;
  __shared__ f16 xt[2][32 * 72];
  f32x4 acc[2][3] = {};
  const float* xb = x + (size_t)b * 524288 + n0;
  int tn = t & 31, fg = t >> 5;   // fg 0..7, handles f-rows fg*8 .. fg*8+7
  const f16* wb = Wopt + (size_t)(w * 3) * 32768 + l15 * 32 + q * 8;

  float rA[8], rB[8];

  auto stageLoad = [&](int c, float* r) {
    const float* base = xb + (size_t)c * 64 * 256 + tn;
    #pragma unroll
    for (int rep = 0; rep < 4; rep++) {
      int fl = fg * 8 + rep * 2;
      r[rep * 2]     = base[(size_t)fl * 256];
      r[rep * 2 + 1] = base[(size_t)(fl + 1) * 256];
    }
  };
  auto stageWrite = [&](const float* r, int p) {
    #pragma unroll
    for (int rep = 0; rep < 4; rep++) {
      int fl = fg * 8 + rep * 2;
      *(uint32_t*)&xt[p][tn * 72 + fl] = packh2(r[rep * 2], r[rep * 2 + 1]);
    }
  };
  auto computeC = [&](int c, int p) {
    #pragma unroll
    for (int ks = 0; ks < 2; ks++) {
      int k0 = ks * 32 + q * 8;
      f16x8 af0 = *(const f16x8*)&xt[p][l15 * 72 + k0];
      f16x8 af1 = *(const f16x8*)&xt[p][(16 + l15) * 72 + k0];
      #pragma unroll
      for (int j = 0; j < 3; j++) {
        f16x8 bf = *(const f16x8*)(wb + (size_t)j * 32768 + (size_t)(c * 2 + ks) * 512);
        acc[0][j] = MFMA(af0, bf, acc[0][j]);
        acc[1][j] = MFMA(af1, bf, acc[1][j]);
      }
    }
  };

  stageLoad(0, rA);
  stageLoad(1, rB);
  stageWrite(rA, 0);
  __syncthreads();

  for (int cc = 0; cc < 16; cc++) {
    int c0 = cc * 2;
    // even iteration: compute c0 from buf0; load c0+2 -> rA; write rB(c0+1) -> buf1
    if (c0 + 2 < 32) stageLoad(c0 + 2, rA);
    stageWrite(rB, 1);
    computeC(c0, 0);
    __syncthreads();
    // odd iteration: compute c0+1 from buf1; load c0+3 -> rB; write rA(c0+2) -> buf0
    int c1 = c0 + 1;
    if (c1 + 2 < 32) stageLoad(c1 + 2, rB);
    if (c1 + 1 < 32) stageWrite(rA, 0);
    computeC(c1, 1);
    __syncthreads();
  }

  // epilogue: sigmoid + store
  #pragma unroll
  for (int nt = 0; nt < 2; nt++)
    #pragma unroll
    for (int j = 0; j < 3; j++) {
      int rr = (w * 3 + j) * 16 + l15;
      float s[4];
      #pragma unroll
      for (int reg = 0; reg < 4; reg++) s[reg] = sigmoidf_(acc[nt][j][reg]);
      int nbase = n0 + nt * 16 + q * 4;
      if (rr < 64) {
        #pragma unroll
        for (int reg = 0; reg < 4; reg++)
          Qt[(size_t)b * 16384 + (size_t)(nbase + reg) * 64 + rr] = (f16)s[reg];
      } else if (rr < 128) {
        #pragma unroll
        for (int reg = 0; reg < 4; reg++)
          Kt[(size_t)b * 16384 + (size_t)(nbase + reg) * 64 + (rr - 64)] = (f16)s[reg];
      } else {
        union { f16 h[4]; uint2 u; } pk;
        #pragma unroll
        for (int reg = 0; reg < 4; reg++) pk.h[reg] = (f16)s[reg];
        *(uint2*)(Vg + (size_t)b * 16384 + (size_t)(rr - 128) * 256 + nbase) = pk.u;
      }
    }
}

// ---------------------------------------------------------------------------
// attn_fused: all 3 layers in one kernel. grid (4,64), 512 threads, ~126 KB
// LDS -> 1 block/CU, all 256 blocks co-resident (safe spin barrier).
// Layer boundary: store M-slice -> threadfence -> atomicAdd(flag[b]) ->
// acquire-spin to 4*(l+1) -> restage. MA holds layer-0 M, MB layer-1 M.
// ---------------------------------------------------------------------------
__global__ __launch_bounds__(512) void attn_fused(const float* __restrict__ x,
    const float* __restrict__ scale, const f16* __restrict__ Wsm,
    const f16* __restrict__ Qtg, const f16* __restrict__ Ktg, const f16* __restrict__ Vgg,
    f16* __restrict__ MA, f16* __restrict__ MB,
    unsigned int* __restrict__ flagg, float* __restrict__ out)
{
  int g = blockIdx.x, b = blockIdx.y, n0 = g * 64;
  int t = threadIdx.x, lane = t & 63, w = t >> 6;
  int l15 = lane & 15, q = lane >> 4;
  __shared__ f16 KT[256 * 72];
  __shared__ f16 SM[256 * 72];
  __shared__ f16 VM[64 * 264];
  __shared__ f16 QT[64 * 72];
  __shared__ f16 OT[64 * 72];
  __shared__ float denomS[64];

  float sinv = 1.0f / scale[b];

  #pragma unroll 1
  for (int l = 0; l < 3; l++) {
    if (t < 64) denomS[t] = 0.0f;

    const f16* Wq = Wsm + (size_t)(l == 1 ? 0 : 3) * 4096;
    const f16* Wk = Wsm + (size_t)(l == 1 ? 1 : 4) * 4096;
    const f16* Wv = Wsm + (size_t)(l == 1 ? 2 : 5) * 4096;
    const f16* Wo = Wsm + (size_t)(l == 0 ? 6 : (l == 1 ? 7 : 8)) * 4096;

    if (l == 0) {
      const uint4* qs = (const uint4*)(Qtg + (size_t)b * 16384 + (size_t)n0 * 64);
      { int n = t >> 3, c = t & 7; *(uint4*)&QT[n * 72 + c * 8] = qs[t]; }
      const uint4* ks = (const uint4*)(Ktg + (size_t)b * 16384);
      const uint4* vs = (const uint4*)(Vgg + (size_t)b * 16384);
      #pragma unroll
      for (int i = 0; i < 4; i++) {
        int id = t + i * 512;
        int m = id >> 3, c = id & 7;
        *(uint4*)&KT[m * 72 + c * 8] = ks[id];
        int r = id >> 5, c2 = id & 31;
        *(uint4*)&VM[r * 264 + c2 * 8] = vs[id];
      }
      __syncthreads();
    } else {
      const f16* Min = (l == 1) ? MA : MB;
      const uint4* ms = (const uint4*)(Min + (size_t)b * 16384);
      #pragma unroll
      for (int i = 0; i < 4; i++) {
        int id = t + i * 512, m = id >> 3, c = id & 7;
        *(uint4*)&SM[m * 72 + c * 8] = ms[id];
      }
      __syncthreads();
      if (w < 4) {
        // KT[m][r] = sigmoid( sum_s M^T[m][s] * Wk[r][s] )
        f16x8 bk[4][2];
        #pragma unroll
        for (int rt = 0; rt < 4; rt++) {
          bk[rt][0] = *(const f16x8*)(Wk + (rt * 16 + l15) * 64 + q * 8);
          bk[rt][1] = *(const f16x8*)(Wk + (rt * 16 + l15) * 64 + 32 + q * 8);
        }
        #pragma unroll
        for (int mi = 0; mi < 4; mi++) {
          int mt = w * 4 + mi;
          f16x8 a0 = *(const f16x8*)&SM[(mt * 16 + l15) * 72 + q * 8];
          f16x8 a1 = *(const f16x8*)&SM[(mt * 16 + l15) * 72 + 32 + q * 8];
          #pragma unroll
          for (int rt = 0; rt < 4; rt++) {
            f32x4 acc = {}; acc = MFMA(a0, bk[rt][0], acc); acc = MFMA(a1, bk[rt][1], acc);
            #pragma unroll
            for (int reg = 0; reg < 4; reg++)
              KT[(mt * 16 + q * 4 + reg) * 72 + rt * 16 + l15] = (f16)sigmoidf_(acc[reg]);
          }
        }
      } else {
        // VM[r][m] = sigmoid( sum_s Wv[r][s] * M^T[m][s] )
        f16x8 av[4][2];
        #pragma unroll
        for (int rt = 0; rt < 4; rt++) {
          av[rt][0] = *(const f16x8*)(Wv + (rt * 16 + l15) * 64 + q * 8);
          av[rt][1] = *(const f16x8*)(Wv + (rt * 16 + l15) * 64 + 32 + q * 8);
        }
        #pragma unroll
        for (int mi = 0; mi < 4; mi++) {
          int mt = (w - 4) * 4 + mi;
          f16x8 b0 = *(const f16x8*)&SM[(mt * 16 + l15) * 72 + q * 8];
          f16x8 b1 = *(const f16x8*)&SM[(mt * 16 + l15) * 72 + 32 + q * 8];
          #pragma unroll
          for (int rt = 0; rt < 4; rt++) {
            f32x4 acc = {}; acc = MFMA(av[rt][0], b0, acc); acc = MFMA(av[rt][1], b1, acc);
            #pragma unroll
            for (int reg = 0; reg < 4; reg++)
              VM[(rt * 16 + q * 4 + reg) * 264 + mt * 16 + l15] = (f16)sigmoidf_(acc[reg]);
          }
        }
      }
      // QT for local rows
      {
        int nt = w >> 1;
        f16x8 a0 = *(const f16x8*)&SM[(n0 + nt * 16 + l15) * 72 + q * 8];
        f16x8 a1 = *(const f16x8*)&SM[(n0 + nt * 16 + l15) * 72 + 32 + q * 8];
        #pragma unroll
        for (int j = 0; j < 2; j++) {
          int rt = (w & 1) * 2 + j;
          f16x8 b0 = *(const f16x8*)(Wq + (rt * 16 + l15) * 64 + q * 8);
          f16x8 b1 = *(const f16x8*)(Wq + (rt * 16 + l15) * 64 + 32 + q * 8);
          f32x4 acc = {}; acc = MFMA(a0, b0, acc); acc = MFMA(a1, b1, acc);
          #pragma unroll
          for (int reg = 0; reg < 4; reg++)
            QT[(nt * 16 + q * 4 + reg) * 72 + rt * 16 + l15] = (f16)sigmoidf_(acc[reg]);
        }
      }
      __syncthreads();
    }

    // S = exp(QK^T * sinv) -> SM as [64][264]; denom via shfl + LDS atomic
    {
      int nt = w >> 1;
      f16x8 a0 = *(const f16x8*)&QT[(nt * 16 + l15) * 72 + q * 8];
      f16x8 a1 = *(const f16x8*)&QT[(nt * 16 + l15) * 72 + 32 + q * 8];
      float dsum[4] = {0.f, 0.f, 0.f, 0.f};
      #pragma unroll
      for (int mi = 0; mi < 8; mi++) {
        int mt = (w & 1) * 8 + mi;
        f16x8 b0 = *(const f16x8*)&KT[(mt * 16 + l15) * 72 + q * 8];
        f16x8 b1 = *(const f16x8*)&KT[(mt * 16 + l15) * 72 + 32 + q * 8];
        f32x4 acc = {}; acc = MFMA(a0, b0, acc); acc = MFMA(a1, b1, acc);
        #pragma unroll
        for (int reg = 0; reg < 4; reg++) {
          float e = __expf(acc[reg] * sinv);
          dsum[reg] += e;
          SM[(nt * 16 + q * 4 + reg) * 264 + mt * 16 + l15] = (f16)e;
        }
      }
      #pragma unroll
      for (int reg = 0; reg < 4; reg++) {
        #pragma unroll
        for (int mask = 1; mask < 16; mask <<= 1) dsum[reg] += __shfl_xor(dsum[reg], mask);
      }
      if (l15 == 0) {
        #pragma unroll
        for (int reg = 0; reg < 4; reg++) atomicAdd(&denomS[nt * 16 + q * 4 + reg], dsum[reg]);
      }
    }
    __syncthreads();

    // AV: o^T[n][r] = sum_m S[n][m] VM[r][m]; normalize -> OT
    {
      int nt = w >> 1;
      f32x4 oacc[2] = {};
      #pragma unroll
      for (int kc = 0; kc < 8; kc++) {
        f16x8 af = *(const f16x8*)&SM[(nt * 16 + l15) * 264 + kc * 32 + q * 8];
        #pragma unroll
        for (int j = 0; j < 2; j++) {
          int rt = (w & 1) * 2 + j;
          f16x8 bf = *(const f16x8*)&VM[(rt * 16 + l15) * 264 + kc * 32 + q * 8];
          oacc[j] = MFMA(af, bf, oacc[j]);
        }
      }
      #pragma unroll
      for (int j = 0; j < 2; j++) {
        int rt = (w & 1) * 2 + j;
        #pragma unroll
        for (int reg = 0; reg < 4; reg++) {
          int row = nt * 16 + q * 4 + reg;
          OT[row * 72 + rt * 16 + l15] = (f16)(oacc[j][reg] / denomS[row]);
        }
      }
    }
    __syncthreads();

    // M'[n][s] = silu( sum_r OT[n][r] Wo[s][r] ) -> Mst (QT reused, stride 64)
    f16* Mst = QT;
    {
      int nt = w >> 1;
      f16x8 a0 = *(const f16x8*)&OT[(nt * 16 + l15) * 72 + q * 8];
      f16x8 a1 = *(const f16x8*)&OT[(nt * 16 + l15) * 72 + 32 + q * 8];
      #pragma unroll
      for (int j = 0; j < 2; j++) {
        int st = (w & 1) * 2 + j;
        f16x8 b0 = *(const f16x8*)(Wo + (st * 16 + l15) * 64 + q * 8);
        f16x8 b1 = *(const f16x8*)(Wo + (st * 16 + l15) * 64 + 32 + q * 8);
        f32x4 acc = {}; acc = MFMA(a0, b0, acc); acc = MFMA(a1, b1, acc);
        #pragma unroll
        for (int reg = 0; reg < 4; reg++) {
          float z = acc[reg];
          Mst[(nt * 16 + q * 4 + reg) * 64 + st * 16 + l15] = (f16)(z * sigmoidf_(z));
        }
      }
    }
    __syncthreads();

    if (l < 2) {
      f16* Mout = (l == 0) ? MA : MB;
      int row = t >> 3, c = t & 7;
      *(uint4*)(Mout + (size_t)b * 16384 + (size_t)(n0 + row) * 64 + c * 8)
          = *(const uint4*)&Mst[row * 64 + c * 8];
      // inter-block (per-batch) barrier: 4 blocks of batch b
      if (t == 0) {
        __threadfence();
        atomicAdd(&flagg[b], 1u);
        unsigned int target = 4u * (unsigned)(l + 1);
        while (__hip_atomic_load(&flagg[b], __ATOMIC_ACQUIRE, __HIP_MEMORY_SCOPE_AGENT) < target)
          __builtin_amdgcn_s_sleep(2);
        __threadfence();
      }
      __syncthreads();
    } else {
      float contrib = 0.0f;
      if (t < 64) {
        int ntok = n0 + t;
        const f16* row = &Mst[t * 64];
        float d[4] = {0, 0, 0, 0}, pp = 0.0f;
        #pragma unroll
        for (int gg = 0; gg < 8; gg++) {
          f16x8 v = *(const f16x8*)(row + gg * 8);
          float ss = 0.0f;
          #pragma unroll
          for (int k = 0; k < 8; k++) { float f = (float)v[k]; ss += f * f; }
          if (gg < 4) d[gg] = ss; else pp += ss;
        }
        int np = ntok >> 1, c0 = (ntok & 1) * 2;
        const float* xb = x + (size_t)b * 524288 + (size_t)c0 * 256;
        float q1a = xb[np], q1b = xb[256 + np];
        float q2a = xb[128 + np], q2b = xb[384 + np];
        contrib = d[0] * (q1a * q1a + q1b * q1b)
                + (d[1] + d[2]) * (q1a * q2a + q1b * q2b)
                + d[3] * (q2a * q2a + q2b * q2b) + pp;
      }
      if (w == 0) {
        #pragma unroll
        for (int off = 32; off; off >>= 1) contrib += __shfl_down(contrib, off);
        if (lane == 0) atomicAdd(out + b, contrib);
      }
    }
  }
}

// ---------------------------------------------------------------------------
extern "C" void kernel_launch(void* const* d_in, const int* in_sizes, int n_in,
                              void* d_out, int out_size, void* d_ws, size_t ws_size,
                              hipStream_t stream) {
  const float* x   = (const float*)d_in[0];
  const float* L   = (const float*)d_in[1];
  const float* Aq  = (const float*)d_in[2];
  const float* Ak  = (const float*)d_in[3];
  const float* Av  = (const float*)d_in[4];
  const float* Aq1 = (const float*)d_in[5];
  const float* Ak1 = (const float*)d_in[6];
  const float* Av1 = (const float*)d_in[7];
  const float* Aq5 = (const float*)d_in[8];
  const float* Ak5 = (const float*)d_in[9];
  const float* Av5 = (const float*)d_in[10];
  const float* Ao  = (const float*)d_in[11];
  const float* Ao1 = (const float*)d_in[12];
  const float* Ao5 = (const float*)d_in[13];

  char* ws = (char*)d_ws;
  float* scale = (float*)ws;                     // 256 B
  f16* Wopt  = (f16*)(ws + 256);                 // 786432 B
  f16* Wsm   = (f16*)(ws + 786688);              // 73728 B
  f16* Qtg   = (f16*)(ws + 860416);              // 2 MB
  f16* Ktg   = (f16*)(ws + 2957568);             // 2 MB
  f16* Vgg   = (f16*)(ws + 5054720);             // 2 MB
  f16* MbufA = (f16*)(ws + 7151872);             // 2 MB
  f16* MbufB = (f16*)(ws + 9249024);             // 2 MB
  unsigned int* flagg = (unsigned int*)(ws + 11346176);  // 256 B
  float* out = (float*)d_out;

  prep_kernel<<<170, 256, 0, stream>>>(L, Aq, Ak, Av, Aq1, Ak1, Av1,
                                       Aq5, Ak5, Av5, Ao, Ao1, Ao5,
                                       scale, Wopt, Wsm, out, flagg);
  qkv1_kernel<<<dim3(8, 64), 256, 0, stream>>>(x, Wopt, Qtg, Ktg, Vgg);
  attn_fused<<<dim3(4, 64), 512, 0, stream>>>(x, scale, Wsm, Qtg, Ktg, Vgg,
                                              MbufA, MbufB, flagg, out);
}